// Round 15
// baseline (4281.469 us; speedup 1.0000x reference)
//
#include <hip/hip_runtime.h>
#include <hip/hip_bf16.h>
#include <math.h>

// ---------------------------------------------------------------------------
// Equivariant 3D CNN (e3nn-style), 5 layers, 48^3 grid, batch 2.
// Round-14 (resubmit; prior attempt hit infra failure): NO LDS STAGING.
// Activations stored padded to 64 ch (128 B/voxel, 16B-aligned bf16x8
// fragment loads). A-fragments read directly from global (L1/L2/L3-resident;
// 22->28 MB act). Removes all main-loop barriers and staging instructions --
// waves fully independent. Wave tile = 2y x 48z (48 MFMA/tap, proven r12).
// LDS = 24 KB epilogue scratch only.
// Evidence: r13 showed 47% occupancy + tripled per-tap overhead = WORSE;
// perf tracks MFMAs/tap/wave; staging loop + barriers are the fixed cost.
// ---------------------------------------------------------------------------

typedef __attribute__((ext_vector_type(8))) short bf16x8;
typedef __attribute__((ext_vector_type(4))) float f32x4;

struct TpPath { int off, ci, co, m1, l1, i2, mo, lo; float alpha; };
struct LinPath { int off, ci, co, m1, l, mo; float norm; };

// alpha = 1/sqrt(m1*1*R_BASIS)
__device__ __constant__ TpPath g_tp[19] = {
  {0,  0,  0, 1, 0, 0, 10, 0, 0.70710678f},
  {20, 0, 20, 1, 0, 0, 10, 0, 0.70710678f},
  {40, 0, 45, 1, 0, 1,  5, 1, 0.70710678f},
  {0,    0,  0, 10, 0, 0, 10, 0, 0.22360680f},
  {200,  0, 20, 10, 0, 0, 10, 0, 0.22360680f},
  {400,  0, 45, 10, 0, 1,  5, 1, 0.22360680f},
  {500, 10, 10, 10, 0, 0, 10, 0, 0.22360680f},
  {700, 10, 30, 10, 0, 1,  5, 1, 0.22360680f},
  {800, 20, 30,  5, 1, 0,  5, 1, 0.31622777f},
  {850, 20, 10,  5, 1, 1, 10, 0, 0.31622777f},
  {950, 20, 45,  5, 1, 1,  5, 1, 0.31622777f},
  {1000,35, 45,  5, 1, 0,  5, 1, 0.31622777f},
  {1050,35,  0,  5, 1, 1, 10, 0, 0.31622777f},
  {1150,35, 20,  5, 1, 1, 10, 0, 0.31622777f},
  {1250,35, 30,  5, 1, 1,  5, 1, 0.31622777f},
  {0,    0, 1, 10, 0, 0, 6, 0, 0.22360680f},
  {120, 10, 0, 10, 0, 0, 1, 0, 0.22360680f},
  {140, 20, 0,  5, 1, 1, 1, 0, 0.31622777f},
  {150, 35, 1,  5, 1, 1, 6, 0, 0.31622777f},
};

// norm = 1/sqrt(m1)
__device__ __constant__ LinPath g_lin[9] = {
  {0,  0,  0, 1, 0, 10, 1.0f},
  {10, 0, 20, 1, 0, 10, 1.0f},
  {0,   0,  0, 10, 0, 10, 0.31622777f},
  {100, 0, 20, 10, 0, 10, 0.31622777f},
  {200,10, 10, 10, 0, 10, 0.31622777f},
  {300,20, 30,  5, 1,  5, 0.44721360f},
  {325,35, 45,  5, 1,  5, 0.44721360f},
  {0,  0, 1, 10, 0, 6, 0.31622777f},
  {60,10, 0, 10, 0, 1, 0.31622777f},
};

__device__ inline float sus_f(float t) { return t > 0.f ? __expf(-1.f / t) : 0.f; }

__global__ void build_tp_kernel(const float* __restrict__ tw, float* __restrict__ kbuf,
                                int CIN, int COUT, int path_base) {
  TpPath p = g_tp[path_base + blockIdx.x];
  const int dl1 = 2 * p.l1 + 1, dlo = 2 * p.lo + 1;
  const int du = p.m1 * dl1, dw = p.mo * dlo;
  const int total = 125 * du * dw;
  const float C0 = 1.14136f * expf(2.0f);
  for (int e = threadIdx.x; e < total; e += blockDim.x) {
    int xyz = e / (du * dw);
    int rem = e % (du * dw);
    int ui = rem / dw, wk = rem % dw;
    int u = ui / dl1, i = ui % dl1;
    int w = wk / dlo, kk = wk % dlo;
    int kx = xyz / 25, ky = (xyz / 5) % 5, kz = xyz % 5;
    float cx = (float)(kx - 2), cy = (float)(ky - 2), cz = (float)(kz - 2);
    float d = sqrtf(cx * cx + cy * cy + cz * cz);
    float t = 1.2f * d;
    float e0 = C0 * sus_f(t) * sus_f(2.f - t);
    float e1 = C0 * sus_f(t - 1.f) * sus_f(3.f - t);
    float radial = e0 * tw[p.off + (0 * p.m1 + u) * p.mo + w] +
                   e1 * tw[p.off + (1 * p.m1 + u) * p.mo + w];
    float invd = (d > 0.f) ? 1.f / d : 0.f;
    const float s3 = 1.7320508f;
    float sh1[3] = { s3 * cy * invd, s3 * cz * invd, s3 * cx * invd };
    float shfac;
    if (p.l1 == 0 && p.i2 == 0)      shfac = 1.f;
    else if (p.l1 == 0)              shfac = sh1[kk];
    else if (p.i2 == 0)              shfac = (i == kk) ? 1.f : 0.f;
    else if (p.lo == 0)              shfac = sh1[i] * 0.57735027f;
    else {
      if (i == kk) shfac = 0.f;
      else {
        int j = 3 - i - kk;
        float sgn = (j == (i + 1) % 3) ? 1.f : -1.f;
        shfac = sgn * sh1[j] * 0.70710678f;
      }
    }
    kbuf[(size_t)(xyz * CIN + p.ci + ui) * COUT + p.co + wk] = p.alpha * radial * shfac;
  }
}

__global__ void set_center_kernel(const float* __restrict__ lw, float* __restrict__ kbuf,
                                  int CIN, int COUT, int lin_base, int nlin) {
  for (int l = 0; l < nlin; l++) {
    LinPath q = g_lin[lin_base + l];
    int dl = 2 * q.l + 1;
    int tot = q.m1 * q.mo * dl;
    for (int e = threadIdx.x; e < tot; e += blockDim.x) {
      int u = e / (q.mo * dl);
      int r = e % (q.mo * dl);
      int w = r / dl, ii = r % dl;
      kbuf[(size_t)(62 * CIN + q.ci + u * dl + ii) * COUT + q.co + w * dl + ii] =
          q.norm * lw[q.off + u * q.mo + w];
    }
  }
}

// fp32 kbuf [125][CIN][COUT] -> bf16 kwbT [125][64 co][64 ci], zero-padded
__global__ void convert_w(const float* __restrict__ kbuf, unsigned short* __restrict__ kwbT,
                          int CIN, int COUT) {
  int idx = blockIdx.x * 256 + threadIdx.x;
  if (idx >= 125 * 64 * 64) return;
  int tap = idx >> 12, co = (idx >> 6) & 63, ci = idx & 63;
  float v = (ci < CIN && co < COUT) ? kbuf[((size_t)tap * CIN + ci) * COUT + co] : 0.f;
  __hip_bfloat16 h = __float2bfloat16(v);
  kwbT[idx] = *(unsigned short*)&h;
}

// layer-0 tap-packed B: [5 dxi][2 mf][64 co][32 k] bf16.
__global__ void build_w0(const float* __restrict__ k0, unsigned short* __restrict__ wb0L) {
  int idx = blockIdx.x * 256 + threadIdx.x;
  if (idx >= 5 * 2 * 64 * 32) return;
  int k = idx & 31, co = (idx >> 5) & 63, mf = (idx >> 11) & 1, dxi = idx >> 12;
  float v = 0.f;
  if (co < 60) {
    if (mf == 0) {
      int dy = k >> 3, dz = k & 7;
      if (dz < 5) v = k0[(size_t)(((dxi * 5 + dy) * 5 + dz)) * 60 + co];
    } else {
      int kg = k >> 3, dz = k & 7;
      if (kg == 0 && dz < 5) v = k0[(size_t)(((dxi * 5 + 4) * 5 + dz)) * 60 + co];
    }
  }
  __hip_bfloat16 h = __float2bfloat16(v);
  wb0L[idx] = *(unsigned short*)&h;
}

__device__ inline float gelu_f(float x) {
  float inner = 0.79788456f * (x + 0.044715f * x * x * x);
  return 0.5f * x * (1.f + tanhf(inner));
}
__device__ inline float sigm_f(float x) { return 1.f / (1.f + __expf(-x)); }

// Gate + coalesced bf16 store, 64-ch padded output (32 dwords/voxel).
// my = per-wave 1536-float LDS scratch: acc words [0,1024), out dwords
// [1024,1536). acc D-layout: z' = 4*kg+reg, co' = lm+16*nt (verified r6).
template <int NT>
__device__ inline void epilogue_gate(f32x4 (&acc)[3][NT], float* my,
                                     unsigned short* out_, int n, int x, int y,
                                     int l, int lm, int kg) {
  unsigned int* myO = (unsigned int*)(my + 1024);
#pragma unroll
  for (int zt = 0; zt < 3; zt++) {              // FULL unroll: acc idx static
#pragma unroll
    for (int nt = 0; nt < NT; nt++)
      *(f32x4*)(my + (lm + 16 * nt) * 16 + 4 * kg) = acc[zt][nt];
    if (l < 16) {                               // lane = z within tile
      const int z = l;
#pragma unroll
      for (int p = 0; p < 25; p++) {            // out channel pair (2p, 2p+1)
        float a0, a1;
        if (p < 5) {                            // gelu on 0:10
          a0 = gelu_f(my[(2 * p) * 16 + z]);
          a1 = gelu_f(my[(2 * p + 1) * 16 + z]);
        } else if (p < 10) {                    // tanh on 10:20
          a0 = tanhf(my[(2 * p) * 16 + z]);
          a1 = tanhf(my[(2 * p + 1) * 16 + z]);
        } else {                                // sigmoid(20+q/3) * a[30+q]
          int q0 = 2 * (p - 10), q1 = q0 + 1;
          a0 = my[(30 + q0) * 16 + z] * sigm_f(my[(20 + q0 / 3) * 16 + z]);
          a1 = my[(30 + q1) * 16 + z] * sigm_f(my[(20 + q1 / 3) * 16 + z]);
        }
        __hip_bfloat162 p2;
        p2.x = __float2bfloat16(a0);
        p2.y = __float2bfloat16(a1);
        myO[z * 32 + p] = *(unsigned int*)&p2;
      }
#pragma unroll
      for (int p = 25; p < 32; p++) myO[z * 32 + p] = 0u;   // ch pad 50..63
    }
    // coalesced copy: 512 contiguous dwords = 16 z * 64 ch bf16
    unsigned int* gout = (unsigned int*)out_ +
        ((size_t)(((n * 48 + x) * 48 + y) * 48 + 16 * zt)) * 32;
#pragma unroll 1
    for (int e = l; e < 512; e += 64) gout[e] = myO[e];
  }
}

// MFMA implicit-GEMM conv, NO staging: A-fragments read directly from the
// 64-ch-padded bf16 activation tensor (128 B/voxel, 16B-aligned loads).
// 256 thr / 4 waves; wave owns 2y x 48z (48 MFMA/tap). grid = 2*48*6 = 576.
// MODE 0: gate -> padded bf16 act out. MODE 1: global sum -> f32 out.
template <int CIN, int COUT, int MODE>
__global__ __launch_bounds__(256, 2)
void conv_mfma(const unsigned short* __restrict__ act, const short* __restrict__ kwbT,
               void* __restrict__ out_) {
  constexpr int NT = (COUT + 15) / 16;     // N tiles of 16
  constexpr int KC = (CIN + 31) / 32;      // K chunks of 32
  __shared__ __align__(16) float EPI[4 * 1536];   // 24 KB epilogue scratch

  const int tid = threadIdx.x;
  const int l = tid & 63;
  const int w = tid >> 6;        // wave: owns y rows {2w, 2w+1} (block-local)
  const int lm = l & 15;
  const int kg = l >> 4;

  const int bid = blockIdx.x;
  const int yb = bid % 6;
  const int x = (bid / 6) % 48;
  const int n = bid / (6 * 48);

  f32x4 acc[2][3][NT];
#pragma unroll
  for (int yy = 0; yy < 2; yy++)
#pragma unroll
    for (int zt = 0; zt < 3; zt++)
#pragma unroll
      for (int nt = 0; nt < NT; nt++) acc[yy][zt][nt] = (f32x4){0.f, 0.f, 0.f, 0.f};

  for (int dxi = 0; dxi < 5; dxi++) {
    const int xin = x + dxi - 2;
    if (xin < 0 || xin >= 48) continue;          // block-uniform
    const int plane = (n * 48 + xin) * 48;       // y-row index base
#pragma unroll 1
    for (int dy = 0; dy < 5; dy++) {
      // per-(yy) row base (wave-uniform validity)
      int rowoff[2]; bool vy[2];
#pragma unroll
      for (int yy = 0; yy < 2; yy++) {
        int yin = 8 * yb + 2 * w + yy + dy - 2;
        vy[yy] = (yin >= 0) && (yin < 48);
        int yc = min(max(yin, 0), 47);
        rowoff[yy] = (plane + yc) * 48 * 64;     // ushort units
      }
      const int tapbase = (dxi * 5 + dy) * 5;
#pragma unroll
      for (int dz = 0; dz < 5; dz++) {
        // ---- B fragments for this tap (global, L1/L2-resident) ----
        bf16x8 bfr[NT * KC];
        {
          const short* wb_ = kwbT + ((size_t)(tapbase + dz) * 64 + lm) * 64 + kg * 8;
#pragma unroll
          for (int nt = 0; nt < NT; nt++)
#pragma unroll
            for (int kc = 0; kc < KC; kc++)
              bfr[nt * KC + kc] = *(const bf16x8*)(wb_ + nt * 16 * 64 + kc * 32);
        }
        // ---- A fragments directly from global (aligned 16B) ----
        bf16x8 afr[2][3][KC];
#pragma unroll
        for (int zt = 0; zt < 3; zt++) {
          const int zraw = 16 * zt + lm + dz - 2;      // input z, may be OOR
          const int zc = min(max(zraw, 0), 47);
          const bool zok = (zraw >= 0) && (zraw < 48); // folds for most zt/dz
#pragma unroll
          for (int yy = 0; yy < 2; yy++) {
            const int base = rowoff[yy] + zc * 64 + kg * 8;
#pragma unroll
            for (int kc = 0; kc < KC; kc++) {
              bf16x8 v = *(const bf16x8*)(act + base + kc * 32);
              afr[yy][zt][kc] = (vy[yy] && zok) ? v : (bf16x8)(short)0;
            }
          }
        }
        // ---- 48 MFMAs (NT=4) ----
#pragma unroll
        for (int yy = 0; yy < 2; yy++)
#pragma unroll
          for (int zt = 0; zt < 3; zt++)
#pragma unroll
            for (int nt = 0; nt < NT; nt++)
#pragma unroll
              for (int kc = 0; kc < KC; kc++)
                acc[yy][zt][nt] = __builtin_amdgcn_mfma_f32_16x16x32_bf16(
                    afr[yy][zt][kc], bfr[nt * KC + kc], acc[yy][zt][nt], 0, 0, 0);
      }
    }
  }

  if constexpr (MODE == 0) {
    float* my = EPI + w * 1536;                 // per-wave scratch, no barrier
#pragma unroll
    for (int yy = 0; yy < 2; yy++)              // static acc idx (rule 20)
      epilogue_gate<NT>(acc[yy], my, (unsigned short*)out_, n, x,
                        8 * yb + 2 * w + yy, l, lm, kg);
  } else {
    // layer 4: channel co=lm lives in lanes {lm, lm+16, lm+32, lm+48}
    float s = 0.f;
#pragma unroll
    for (int yy = 0; yy < 2; yy++)
#pragma unroll
      for (int zt = 0; zt < 3; zt++)
#pragma unroll
        for (int r = 0; r < 4; r++) s += acc[yy][zt][0][r];
    s += __shfl_xor(s, 16);
    s += __shfl_xor(s, 32);
    if (l < 7) atomicAdd(&((float*)out_)[n * 7 + l], s);
  }
}

// Layer 0 (CIN=1): taps packed into MFMA-K (round-7 structure; writes the
// 64-ch padded activation layout via the shared epilogue).
__global__ __launch_bounds__(256, 4)
void conv0_mfma(const float* __restrict__ in_, const short* __restrict__ wb0L,
                unsigned short* __restrict__ out_) {
  __shared__ float A0[8 * 72];                 // [yi][zz] fp32, zz 52..71 = 0
  __shared__ __align__(16) float outbuf0[4 * 1536];

  const int tid = threadIdx.x;
  const int l = tid & 63;
  const int w = tid >> 6;
  const int lm = l & 15;
  const int kg = l >> 4;
  const int yb = blockIdx.x % 12;
  const int x = (blockIdx.x / 12) % 48;
  const int n = blockIdx.x / (12 * 48);

  f32x4 acc[3][4];
#pragma unroll
  for (int zt = 0; zt < 3; zt++)
#pragma unroll
    for (int nt = 0; nt < 4; nt++) acc[zt][nt] = (f32x4){0.f, 0.f, 0.f, 0.f};

  for (int dxi = 0; dxi < 5; dxi++) {
    int xin = x + dxi - 2;
    if (xin < 0 || xin >= 48) continue;
    __syncthreads();
    for (int e = tid; e < 8 * 72; e += 256) {
      int yi = e / 72, zz = e % 72;
      int yin = 4 * yb + yi - 2, zin = zz - 2;
      A0[e] = (yin >= 0 && yin < 48 && zin >= 0 && zin < 48)
                  ? in_[(size_t)((n * 48 + xin) * 48 + yin) * 48 + zin] : 0.f;
    }
    __syncthreads();
#pragma unroll
    for (int mf = 0; mf < 2; mf++) {
      const short* wbp = wb0L + ((size_t)(dxi * 2 + mf) * 64 + lm) * 32 + kg * 8;
      bf16x8 bfr[4];
#pragma unroll
      for (int nt = 0; nt < 4; nt++) bfr[nt] = *(const bf16x8*)(wbp + nt * 16 * 32);
      const int row = mf ? (w + 4) : (w + kg);
#pragma unroll
      for (int zt = 0; zt < 3; zt++) {
        const float* ap = A0 + row * 72 + 16 * zt + lm;
        union { bf16x8 v; unsigned short s[8]; } af;
#pragma unroll
        for (int j = 0; j < 8; j++) {
          __hip_bfloat16 h = __float2bfloat16(ap[j]);
          af.s[j] = *(unsigned short*)&h;
        }
#pragma unroll
        for (int nt = 0; nt < 4; nt++)
          acc[zt][nt] = __builtin_amdgcn_mfma_f32_16x16x32_bf16(
              af.v, bfr[nt], acc[zt][nt], 0, 0, 0);
      }
    }
  }

  float* my = outbuf0 + w * 1536;
  epilogue_gate<4>(acc, my, out_, n, x, 4 * yb + w, l, lm, kg);
}

extern "C" void kernel_launch(void* const* d_in, const int* in_sizes, int n_in,
                              void* d_out, int out_size, void* d_ws, size_t ws_size,
                              hipStream_t stream) {
  // setup_inputs() dict order (INTERLEAVED): x, tp_w0, lin_w0, tp_w1, lin_w1, ...
  const float* x   = (const float*)d_in[0];
  const float* tw0 = (const float*)d_in[1];
  const float* lw0 = (const float*)d_in[2];
  const float* tw1 = (const float*)d_in[3];
  const float* lw1 = (const float*)d_in[4];
  const float* tw2 = (const float*)d_in[5];
  const float* lw2 = (const float*)d_in[6];
  const float* tw3 = (const float*)d_in[7];
  const float* lw3 = (const float*)d_in[8];
  const float* tw4 = (const float*)d_in[9];
  const float* lw4 = (const float*)d_in[10];

  float* ws = (float*)d_ws;
  float* k0 = ws;                 // 125*1*60   = 7500
  float* k1 = k0 + 7500;          // 125*50*60  = 375000
  float* k2 = k1 + 375000;
  float* k3 = k2 + 375000;
  float* k4 = k3 + 375000;        // 125*50*7   = 43750  (end: 1,176,250)
  // 64-ch-padded bf16 activations: 2*48^3*64 = 14,155,776 ushorts each
  unsigned short* actA = (unsigned short*)(ws + 1200000);
  unsigned short* actB = actA + 14155776;     // ends float offset 15,355,776
  // bf16 transposed weights [125][64][64] per layer
  unsigned short* wb1 = (unsigned short*)(ws + 15360000);
  unsigned short* wb2 = wb1 + 512000;
  unsigned short* wb3 = wb2 + 512000;
  unsigned short* wb4 = wb3 + 512000;
  unsigned short* wb0L = wb4 + 512000;        // [5][2][64][32] = 20480

  hipMemsetAsync(ws, 0, (size_t)1176250 * sizeof(float), stream);
  hipMemsetAsync(d_out, 0, (size_t)out_size * sizeof(float), stream);

  build_tp_kernel<<<3, 128, 0, stream>>>(tw0, k0, 1, 60, 0);
  build_tp_kernel<<<12, 128, 0, stream>>>(tw1, k1, 50, 60, 3);
  build_tp_kernel<<<12, 128, 0, stream>>>(tw2, k2, 50, 60, 3);
  build_tp_kernel<<<12, 128, 0, stream>>>(tw3, k3, 50, 60, 3);
  build_tp_kernel<<<4, 128, 0, stream>>>(tw4, k4, 50, 7, 15);
  set_center_kernel<<<1, 256, 0, stream>>>(lw0, k0, 1, 60, 0, 2);
  set_center_kernel<<<1, 256, 0, stream>>>(lw1, k1, 50, 60, 2, 5);
  set_center_kernel<<<1, 256, 0, stream>>>(lw2, k2, 50, 60, 2, 5);
  set_center_kernel<<<1, 256, 0, stream>>>(lw3, k3, 50, 60, 2, 5);
  set_center_kernel<<<1, 256, 0, stream>>>(lw4, k4, 50, 7, 7, 2);

  convert_w<<<2000, 256, 0, stream>>>(k1, wb1, 50, 60);
  convert_w<<<2000, 256, 0, stream>>>(k2, wb2, 50, 60);
  convert_w<<<2000, 256, 0, stream>>>(k3, wb3, 50, 60);
  convert_w<<<2000, 256, 0, stream>>>(k4, wb4, 50, 7);
  build_w0<<<80, 256, 0, stream>>>(k0, wb0L);

  const int grid0 = 2 * 48 * 12;  // conv0: (n, x, y-quad), 1 y per wave
  const int grid  = 2 * 48 * 6;   // mid/last: (n, x, y-octant), 2 y per wave
  conv0_mfma<<<grid0, 256, 0, stream>>>(x, (const short*)wb0L, actA);
  conv_mfma<50, 60, 0><<<grid, 256, 0, stream>>>(actA, (const short*)wb1, actB);
  conv_mfma<50, 60, 0><<<grid, 256, 0, stream>>>(actB, (const short*)wb2, actA);
  conv_mfma<50, 60, 0><<<grid, 256, 0, stream>>>(actA, (const short*)wb3, actB);
  conv_mfma<50, 7, 1><<<grid, 256, 0, stream>>>(actB, (const short*)wb4, d_out);
}

// Round 16
// 3463.593 us; speedup vs baseline: 1.2361x; 1.2361x over previous
//
#include <hip/hip_runtime.h>
#include <hip/hip_bf16.h>
#include <math.h>

// ---------------------------------------------------------------------------
// Equivariant 3D CNN (e3nn-style), 5 layers, 48^3 grid, batch 2.
// Round-16: address-engineered main loop.
//  - LDS A-tile z-major [12 y][8 u][53 z] x 16B units (u = 8-ci group; z
//    padded to 53 to spread banks). A-fragment reads = per-thread base +
//    dy-uniform add + COMPILE-TIME immediate offsets (kc/zt/dz) -> ~0 VALU.
//    No XOR swizzle, no clamps, no masks (halos staged as zeros).
//  - 8 waves/block (512 thr), wave = 1y x 48z (24 MFMA/tap), 2 waves/SIMD
//    guaranteed. Staging = {16B global load -> ds_write_b128} x ~10/thread.
//  Evidence: r12/r13/r15 all show ~430 VALU-issue cyc per tap per wave
//  (address rebuild: XOR, clamps, cndmask, 64-bit math) vs ~50 needed;
//  stalls + VALU dominate at any occupancy <= 2 waves/SIMD.
// ---------------------------------------------------------------------------

typedef __attribute__((ext_vector_type(8))) short bf16x8;
typedef __attribute__((ext_vector_type(4))) float f32x4;
typedef __attribute__((ext_vector_type(4))) unsigned int u32x4;

struct TpPath { int off, ci, co, m1, l1, i2, mo, lo; float alpha; };
struct LinPath { int off, ci, co, m1, l, mo; float norm; };

// alpha = 1/sqrt(m1*1*R_BASIS)
__device__ __constant__ TpPath g_tp[19] = {
  {0,  0,  0, 1, 0, 0, 10, 0, 0.70710678f},
  {20, 0, 20, 1, 0, 0, 10, 0, 0.70710678f},
  {40, 0, 45, 1, 0, 1,  5, 1, 0.70710678f},
  {0,    0,  0, 10, 0, 0, 10, 0, 0.22360680f},
  {200,  0, 20, 10, 0, 0, 10, 0, 0.22360680f},
  {400,  0, 45, 10, 0, 1,  5, 1, 0.22360680f},
  {500, 10, 10, 10, 0, 0, 10, 0, 0.22360680f},
  {700, 10, 30, 10, 0, 1,  5, 1, 0.22360680f},
  {800, 20, 30,  5, 1, 0,  5, 1, 0.31622777f},
  {850, 20, 10,  5, 1, 1, 10, 0, 0.31622777f},
  {950, 20, 45,  5, 1, 1,  5, 1, 0.31622777f},
  {1000,35, 45,  5, 1, 0,  5, 1, 0.31622777f},
  {1050,35,  0,  5, 1, 1, 10, 0, 0.31622777f},
  {1150,35, 20,  5, 1, 1, 10, 0, 0.31622777f},
  {1250,35, 30,  5, 1, 1,  5, 1, 0.31622777f},
  {0,    0, 1, 10, 0, 0, 6, 0, 0.22360680f},
  {120, 10, 0, 10, 0, 0, 1, 0, 0.22360680f},
  {140, 20, 0,  5, 1, 1, 1, 0, 0.31622777f},
  {150, 35, 1,  5, 1, 1, 6, 0, 0.31622777f},
};

// norm = 1/sqrt(m1)
__device__ __constant__ LinPath g_lin[9] = {
  {0,  0,  0, 1, 0, 10, 1.0f},
  {10, 0, 20, 1, 0, 10, 1.0f},
  {0,   0,  0, 10, 0, 10, 0.31622777f},
  {100, 0, 20, 10, 0, 10, 0.31622777f},
  {200,10, 10, 10, 0, 10, 0.31622777f},
  {300,20, 30,  5, 1,  5, 0.44721360f},
  {325,35, 45,  5, 1,  5, 0.44721360f},
  {0,  0, 1, 10, 0, 6, 0.31622777f},
  {60,10, 0, 10, 0, 1, 0.31622777f},
};

__device__ inline float sus_f(float t) { return t > 0.f ? __expf(-1.f / t) : 0.f; }

__global__ void build_tp_kernel(const float* __restrict__ tw, float* __restrict__ kbuf,
                                int CIN, int COUT, int path_base) {
  TpPath p = g_tp[path_base + blockIdx.x];
  const int dl1 = 2 * p.l1 + 1, dlo = 2 * p.lo + 1;
  const int du = p.m1 * dl1, dw = p.mo * dlo;
  const int total = 125 * du * dw;
  const float C0 = 1.14136f * expf(2.0f);
  for (int e = threadIdx.x; e < total; e += blockDim.x) {
    int xyz = e / (du * dw);
    int rem = e % (du * dw);
    int ui = rem / dw, wk = rem % dw;
    int u = ui / dl1, i = ui % dl1;
    int w = wk / dlo, kk = wk % dlo;
    int kx = xyz / 25, ky = (xyz / 5) % 5, kz = xyz % 5;
    float cx = (float)(kx - 2), cy = (float)(ky - 2), cz = (float)(kz - 2);
    float d = sqrtf(cx * cx + cy * cy + cz * cz);
    float t = 1.2f * d;
    float e0 = C0 * sus_f(t) * sus_f(2.f - t);
    float e1 = C0 * sus_f(t - 1.f) * sus_f(3.f - t);
    float radial = e0 * tw[p.off + (0 * p.m1 + u) * p.mo + w] +
                   e1 * tw[p.off + (1 * p.m1 + u) * p.mo + w];
    float invd = (d > 0.f) ? 1.f / d : 0.f;
    const float s3 = 1.7320508f;
    float sh1[3] = { s3 * cy * invd, s3 * cz * invd, s3 * cx * invd };
    float shfac;
    if (p.l1 == 0 && p.i2 == 0)      shfac = 1.f;
    else if (p.l1 == 0)              shfac = sh1[kk];
    else if (p.i2 == 0)              shfac = (i == kk) ? 1.f : 0.f;
    else if (p.lo == 0)              shfac = sh1[i] * 0.57735027f;
    else {
      if (i == kk) shfac = 0.f;
      else {
        int j = 3 - i - kk;
        float sgn = (j == (i + 1) % 3) ? 1.f : -1.f;
        shfac = sgn * sh1[j] * 0.70710678f;
      }
    }
    kbuf[(size_t)(xyz * CIN + p.ci + ui) * COUT + p.co + wk] = p.alpha * radial * shfac;
  }
}

__global__ void set_center_kernel(const float* __restrict__ lw, float* __restrict__ kbuf,
                                  int CIN, int COUT, int lin_base, int nlin) {
  for (int l = 0; l < nlin; l++) {
    LinPath q = g_lin[lin_base + l];
    int dl = 2 * q.l + 1;
    int tot = q.m1 * q.mo * dl;
    for (int e = threadIdx.x; e < tot; e += blockDim.x) {
      int u = e / (q.mo * dl);
      int r = e % (q.mo * dl);
      int w = r / dl, ii = r % dl;
      kbuf[(size_t)(62 * CIN + q.ci + u * dl + ii) * COUT + q.co + w * dl + ii] =
          q.norm * lw[q.off + u * q.mo + w];
    }
  }
}

// fp32 kbuf [125][CIN][COUT] -> bf16 kwbT [125][64 co][64 ci], zero-padded
__global__ void convert_w(const float* __restrict__ kbuf, unsigned short* __restrict__ kwbT,
                          int CIN, int COUT) {
  int idx = blockIdx.x * 256 + threadIdx.x;
  if (idx >= 125 * 64 * 64) return;
  int tap = idx >> 12, co = (idx >> 6) & 63, ci = idx & 63;
  float v = (ci < CIN && co < COUT) ? kbuf[((size_t)tap * CIN + ci) * COUT + co] : 0.f;
  __hip_bfloat16 h = __float2bfloat16(v);
  kwbT[idx] = *(unsigned short*)&h;
}

// layer-0 tap-packed B: [5 dxi][2 mf][64 co][32 k] bf16.
__global__ void build_w0(const float* __restrict__ k0, unsigned short* __restrict__ wb0L) {
  int idx = blockIdx.x * 256 + threadIdx.x;
  if (idx >= 5 * 2 * 64 * 32) return;
  int k = idx & 31, co = (idx >> 5) & 63, mf = (idx >> 11) & 1, dxi = idx >> 12;
  float v = 0.f;
  if (co < 60) {
    if (mf == 0) {
      int dy = k >> 3, dz = k & 7;
      if (dz < 5) v = k0[(size_t)(((dxi * 5 + dy) * 5 + dz)) * 60 + co];
    } else {
      int kg = k >> 3, dz = k & 7;
      if (kg == 0 && dz < 5) v = k0[(size_t)(((dxi * 5 + 4) * 5 + dz)) * 60 + co];
    }
  }
  __hip_bfloat16 h = __float2bfloat16(v);
  wb0L[idx] = *(unsigned short*)&h;
}

__device__ inline float gelu_f(float x) {
  float inner = 0.79788456f * (x + 0.044715f * x * x * x);
  return 0.5f * x * (1.f + tanhf(inner));
}
__device__ inline float sigm_f(float x) { return 1.f / (1.f + __expf(-x)); }

// Gate + coalesced bf16 store, 64-ch padded output (32 dwords/voxel).
// my = per-wave 1536-float LDS scratch: acc words [0,1024), out dwords
// [1024,1536). acc D-layout: z' = 4*kg+reg, co' = lm+16*nt (verified r6).
template <int NT>
__device__ inline void epilogue_gate(f32x4 (&acc)[3][NT], float* my,
                                     unsigned short* out_, int n, int x, int y,
                                     int l, int lm, int kg) {
  unsigned int* myO = (unsigned int*)(my + 1024);
#pragma unroll
  for (int zt = 0; zt < 3; zt++) {              // FULL unroll: acc idx static
#pragma unroll
    for (int nt = 0; nt < NT; nt++)
      *(f32x4*)(my + (lm + 16 * nt) * 16 + 4 * kg) = acc[zt][nt];
    if (l < 16) {                               // lane = z within tile
      const int z = l;
#pragma unroll
      for (int p = 0; p < 25; p++) {            // out channel pair (2p, 2p+1)
        float a0, a1;
        if (p < 5) {                            // gelu on 0:10
          a0 = gelu_f(my[(2 * p) * 16 + z]);
          a1 = gelu_f(my[(2 * p + 1) * 16 + z]);
        } else if (p < 10) {                    // tanh on 10:20
          a0 = tanhf(my[(2 * p) * 16 + z]);
          a1 = tanhf(my[(2 * p + 1) * 16 + z]);
        } else {                                // sigmoid(20+q/3) * a[30+q]
          int q0 = 2 * (p - 10), q1 = q0 + 1;
          a0 = my[(30 + q0) * 16 + z] * sigm_f(my[(20 + q0 / 3) * 16 + z]);
          a1 = my[(30 + q1) * 16 + z] * sigm_f(my[(20 + q1 / 3) * 16 + z]);
        }
        __hip_bfloat162 p2;
        p2.x = __float2bfloat16(a0);
        p2.y = __float2bfloat16(a1);
        myO[z * 32 + p] = *(unsigned int*)&p2;
      }
#pragma unroll
      for (int p = 25; p < 32; p++) myO[z * 32 + p] = 0u;   // ch pad 50..63
    }
    // coalesced copy: 512 contiguous dwords = 16 z * 64 ch bf16
    unsigned int* gout = (unsigned int*)out_ +
        ((size_t)(((n * 48 + x) * 48 + y) * 48 + 16 * zt)) * 32;
#pragma unroll 1
    for (int e = l; e < 512; e += 64) gout[e] = myO[e];
  }
}

// MFMA implicit-GEMM conv. 512 thr = 8 waves (2/SIMD guaranteed); wave owns
// 1y x 48z (24 MFMA/tap). A staged per dxi in z-major LDS [12y][8u][53z]x16B;
// fragment reads use immediate offsets only. grid = 2*48*6 = 576.
// MODE 0: gate -> padded bf16 act out. MODE 1: global sum -> f32 out.
template <int CIN, int COUT, int MODE>
__global__ __launch_bounds__(512, 2)
void conv_mfma(const unsigned short* __restrict__ act, const short* __restrict__ kwbT,
               void* __restrict__ out_) {
  constexpr int NT = (COUT + 15) / 16;     // N tiles of 16
  constexpr int KC = (CIN + 31) / 32;      // K chunks of 32
  constexpr int NUNIT = 12 * 8 * 53;       // 5088 16B units = 81408 B
  __shared__ __align__(16) u32x4 SMEM[NUNIT];   // epilogue aliases (48 KB)

  const int tid = threadIdx.x;
  const int l = tid & 63;
  const int w = tid >> 6;        // wave 0..7: owns block-local y row w
  const int lm = l & 15;
  const int kg = l >> 4;

  const int bid = blockIdx.x;
  const int yb = bid % 6;
  const int x = (bid / 6) % 48;
  const int n = bid / (6 * 48);

  f32x4 acc[3][NT];
#pragma unroll
  for (int zt = 0; zt < 3; zt++)
#pragma unroll
    for (int nt = 0; nt < NT; nt++) acc[zt][nt] = (f32x4){0.f, 0.f, 0.f, 0.f};

  // per-thread A base (ushort units): [yrow][u][53 z] -> yrow*8*53*8? strides
  // in ushorts: z: 8, u: 424, yrow: 3392. base covers (yrow=w piece later).
  const int aThr = kg * 424 + lm * 8;      // kg -> u low part, lm -> z part

  for (int dxi = 0; dxi < 5; dxi++) {
    const int xin = x + dxi - 2;
    if (xin < 0 || xin >= 48) continue;          // block-uniform
    const int plane = (n * 48 + xin) * 48;
    __syncthreads();                              // prior tap-loop done w/ SMEM
    // ---- stage plane: unit e = (yi*8+u)*53+zz; 16B global -> ds_write ----
    for (int e = tid; e < NUNIT; e += 512) {
      int yi = e / 424;                           // 8*53
      int rem = e % 424;
      int u = rem / 53, zz = rem % 53;
      int yin = 8 * yb + yi - 2;
      int zin = zz - 2;
      u32x4 val = (u32x4){0u, 0u, 0u, 0u};
      if (yin >= 0 && yin < 48 && zin >= 0 && zin < 48)
        val = *(const u32x4*)(act + ((size_t)(plane + yin) * 48 + zin) * 64 + u * 8);
      SMEM[e] = val;
    }
    __syncthreads();

    const short* As = (const short*)SMEM;
#pragma unroll 1
    for (int dy = 0; dy < 5; dy++) {
      const short* Abase = As + (w + dy) * 3392 + aThr;  // 1 add per dy
      const int tapbase = (dxi * 5 + dy) * 5;
#pragma unroll
      for (int dz = 0; dz < 5; dz++) {
        // ---- B fragments (global, uniform base + lane offset) ----
        bf16x8 bfr[NT * KC];
        {
          const short* wb_ = kwbT + ((size_t)(tapbase + dz) << 12) + lm * 64 + kg * 8;
#pragma unroll
          for (int nt = 0; nt < NT; nt++)
#pragma unroll
            for (int kc = 0; kc < KC; kc++)
              bfr[nt * KC + kc] = *(const bf16x8*)(wb_ + nt * 1024 + kc * 32);
        }
        // ---- A fragments: immediate offsets only (kc*1696 + zt*128 + dz*8) ----
        bf16x8 afr[3][KC];
#pragma unroll
        for (int zt = 0; zt < 3; zt++)
#pragma unroll
          for (int kc = 0; kc < KC; kc++)
            afr[zt][kc] = *(const bf16x8*)(Abase + kc * 1696 + zt * 128 + dz * 8);
        // ---- 24 MFMAs (NT=4) ----
#pragma unroll
        for (int zt = 0; zt < 3; zt++)
#pragma unroll
          for (int nt = 0; nt < NT; nt++)
#pragma unroll
            for (int kc = 0; kc < KC; kc++)
              acc[zt][nt] = __builtin_amdgcn_mfma_f32_16x16x32_bf16(
                  afr[zt][kc], bfr[nt * KC + kc], acc[zt][nt], 0, 0, 0);
      }
    }
  }

  if constexpr (MODE == 0) {
    __syncthreads();                            // everyone done reading SMEM
    float* my = (float*)SMEM + w * 1536;        // 8 waves * 6 KB = 48 KB alias
    epilogue_gate<NT>(acc, my, (unsigned short*)out_, n, x, 8 * yb + w,
                      l, lm, kg);
  } else {
    // layer 4: channel co=lm lives in lanes {lm, lm+16, lm+32, lm+48}
    float s = 0.f;
#pragma unroll
    for (int zt = 0; zt < 3; zt++)
#pragma unroll
      for (int r = 0; r < 4; r++) s += acc[zt][0][r];
    s += __shfl_xor(s, 16);
    s += __shfl_xor(s, 32);
    if (l < 7) atomicAdd(&((float*)out_)[n * 7 + l], s);
  }
}

// Layer 0 (CIN=1): taps packed into MFMA-K (round-7 structure; writes the
// 64-ch padded activation layout via the shared epilogue).
__global__ __launch_bounds__(256, 4)
void conv0_mfma(const float* __restrict__ in_, const short* __restrict__ wb0L,
                unsigned short* __restrict__ out_) {
  __shared__ float A0[8 * 72];                 // [yi][zz] fp32, zz 52..71 = 0
  __shared__ __align__(16) float outbuf0[4 * 1536];

  const int tid = threadIdx.x;
  const int l = tid & 63;
  const int w = tid >> 6;
  const int lm = l & 15;
  const int kg = l >> 4;
  const int yb = blockIdx.x % 12;
  const int x = (blockIdx.x / 12) % 48;
  const int n = blockIdx.x / (12 * 48);

  f32x4 acc[3][4];
#pragma unroll
  for (int zt = 0; zt < 3; zt++)
#pragma unroll
    for (int nt = 0; nt < 4; nt++) acc[zt][nt] = (f32x4){0.f, 0.f, 0.f, 0.f};

  for (int dxi = 0; dxi < 5; dxi++) {
    int xin = x + dxi - 2;
    if (xin < 0 || xin >= 48) continue;
    __syncthreads();
    for (int e = tid; e < 8 * 72; e += 256) {
      int yi = e / 72, zz = e % 72;
      int yin = 4 * yb + yi - 2, zin = zz - 2;
      A0[e] = (yin >= 0 && yin < 48 && zin >= 0 && zin < 48)
                  ? in_[(size_t)((n * 48 + xin) * 48 + yin) * 48 + zin] : 0.f;
    }
    __syncthreads();
#pragma unroll
    for (int mf = 0; mf < 2; mf++) {
      const short* wbp = wb0L + ((size_t)(dxi * 2 + mf) * 64 + lm) * 32 + kg * 8;
      bf16x8 bfr[4];
#pragma unroll
      for (int nt = 0; nt < 4; nt++) bfr[nt] = *(const bf16x8*)(wbp + nt * 16 * 32);
      const int row = mf ? (w + 4) : (w + kg);
#pragma unroll
      for (int zt = 0; zt < 3; zt++) {
        const float* ap = A0 + row * 72 + 16 * zt + lm;
        union { bf16x8 v; unsigned short s[8]; } af;
#pragma unroll
        for (int j = 0; j < 8; j++) {
          __hip_bfloat16 h = __float2bfloat16(ap[j]);
          af.s[j] = *(unsigned short*)&h;
        }
#pragma unroll
        for (int nt = 0; nt < 4; nt++)
          acc[zt][nt] = __builtin_amdgcn_mfma_f32_16x16x32_bf16(
              af.v, bfr[nt], acc[zt][nt], 0, 0, 0);
      }
    }
  }

  float* my = outbuf0 + w * 1536;
  epilogue_gate<4>(acc, my, out_, n, x, 4 * yb + w, l, lm, kg);
}

extern "C" void kernel_launch(void* const* d_in, const int* in_sizes, int n_in,
                              void* d_out, int out_size, void* d_ws, size_t ws_size,
                              hipStream_t stream) {
  // setup_inputs() dict order (INTERLEAVED): x, tp_w0, lin_w0, tp_w1, lin_w1, ...
  const float* x   = (const float*)d_in[0];
  const float* tw0 = (const float*)d_in[1];
  const float* lw0 = (const float*)d_in[2];
  const float* tw1 = (const float*)d_in[3];
  const float* lw1 = (const float*)d_in[4];
  const float* tw2 = (const float*)d_in[5];
  const float* lw2 = (const float*)d_in[6];
  const float* tw3 = (const float*)d_in[7];
  const float* lw3 = (const float*)d_in[8];
  const float* tw4 = (const float*)d_in[9];
  const float* lw4 = (const float*)d_in[10];

  float* ws = (float*)d_ws;
  float* k0 = ws;                 // 125*1*60   = 7500
  float* k1 = k0 + 7500;          // 125*50*60  = 375000
  float* k2 = k1 + 375000;
  float* k3 = k2 + 375000;
  float* k4 = k3 + 375000;        // 125*50*7   = 43750  (end: 1,176,250)
  // 64-ch-padded bf16 activations: 2*48^3*64 = 14,155,776 ushorts each
  unsigned short* actA = (unsigned short*)(ws + 1200000);
  unsigned short* actB = actA + 14155776;     // ends float offset 15,355,776
  // bf16 transposed weights [125][64][64] per layer
  unsigned short* wb1 = (unsigned short*)(ws + 15360000);
  unsigned short* wb2 = wb1 + 512000;
  unsigned short* wb3 = wb2 + 512000;
  unsigned short* wb4 = wb3 + 512000;
  unsigned short* wb0L = wb4 + 512000;        // [5][2][64][32] = 20480

  hipMemsetAsync(ws, 0, (size_t)1176250 * sizeof(float), stream);
  hipMemsetAsync(d_out, 0, (size_t)out_size * sizeof(float), stream);

  build_tp_kernel<<<3, 128, 0, stream>>>(tw0, k0, 1, 60, 0);
  build_tp_kernel<<<12, 128, 0, stream>>>(tw1, k1, 50, 60, 3);
  build_tp_kernel<<<12, 128, 0, stream>>>(tw2, k2, 50, 60, 3);
  build_tp_kernel<<<12, 128, 0, stream>>>(tw3, k3, 50, 60, 3);
  build_tp_kernel<<<4, 128, 0, stream>>>(tw4, k4, 50, 7, 15);
  set_center_kernel<<<1, 256, 0, stream>>>(lw0, k0, 1, 60, 0, 2);
  set_center_kernel<<<1, 256, 0, stream>>>(lw1, k1, 50, 60, 2, 5);
  set_center_kernel<<<1, 256, 0, stream>>>(lw2, k2, 50, 60, 2, 5);
  set_center_kernel<<<1, 256, 0, stream>>>(lw3, k3, 50, 60, 2, 5);
  set_center_kernel<<<1, 256, 0, stream>>>(lw4, k4, 50, 7, 7, 2);

  convert_w<<<2000, 256, 0, stream>>>(k1, wb1, 50, 60);
  convert_w<<<2000, 256, 0, stream>>>(k2, wb2, 50, 60);
  convert_w<<<2000, 256, 0, stream>>>(k3, wb3, 50, 60);
  convert_w<<<2000, 256, 0, stream>>>(k4, wb4, 50, 7);
  build_w0<<<80, 256, 0, stream>>>(k0, wb0L);

  const int grid0 = 2 * 48 * 12;  // conv0: (n, x, y-quad), 1 y per wave
  const int grid  = 2 * 48 * 6;   // mid/last: (n, x, y-octant), 512 thr
  conv0_mfma<<<grid0, 256, 0, stream>>>(x, (const short*)wb0L, actA);
  conv_mfma<50, 60, 0><<<grid, 512, 0, stream>>>(actA, (const short*)wb1, actB);
  conv_mfma<50, 60, 0><<<grid, 512, 0, stream>>>(actB, (const short*)wb2, actA);
  conv_mfma<50, 60, 0><<<grid, 512, 0, stream>>>(actA, (const short*)wb3, actB);
  conv_mfma<50, 7, 1><<<grid, 512, 0, stream>>>(actB, (const short*)wb4, d_out);
}

// Round 17
// 2274.778 us; speedup vs baseline: 1.8821x; 1.5226x over previous
//
#include <hip/hip_runtime.h>
#include <hip/hip_bf16.h>
#include <math.h>

// ---------------------------------------------------------------------------
// Equivariant 3D CNN (e3nn-style), 5 layers, 48^3 grid, batch 2.
// Round-17: co-split r12 into a 512-thread block.
//  - Block = 8y x 48z, 8 waves (2/SIMD GUARANTEED -- only 512-thr blocks ever
//    exceeded 14% occupancy: r13/r16). Wave w: y-pair (w&3), co-half (w>>2).
//  - Staging + A-fragment path byte-identical to r12 (1.3M conflicts, proven);
//    24 MFMA/tap/wave -> 48 MFMA/tap/SIMD = r12 arithmetic at 2x TLP.
//  - Gate couples co-halves -> paired-wave epilogue via double-buffered LDS.
//  Evidence: r16's z-major layout hit 21.4M bank conflicts (reverted); r8-r12
//  4-wave blocks never co-scheduled 2 blocks/CU (13.8% occupancy invariant).
// ---------------------------------------------------------------------------

typedef __attribute__((ext_vector_type(8))) short bf16x8;
typedef __attribute__((ext_vector_type(4))) float f32x4;

struct TpPath { int off, ci, co, m1, l1, i2, mo, lo; float alpha; };
struct LinPath { int off, ci, co, m1, l, mo; float norm; };

// alpha = 1/sqrt(m1*1*R_BASIS)
__device__ __constant__ TpPath g_tp[19] = {
  {0,  0,  0, 1, 0, 0, 10, 0, 0.70710678f},
  {20, 0, 20, 1, 0, 0, 10, 0, 0.70710678f},
  {40, 0, 45, 1, 0, 1,  5, 1, 0.70710678f},
  {0,    0,  0, 10, 0, 0, 10, 0, 0.22360680f},
  {200,  0, 20, 10, 0, 0, 10, 0, 0.22360680f},
  {400,  0, 45, 10, 0, 1,  5, 1, 0.22360680f},
  {500, 10, 10, 10, 0, 0, 10, 0, 0.22360680f},
  {700, 10, 30, 10, 0, 1,  5, 1, 0.22360680f},
  {800, 20, 30,  5, 1, 0,  5, 1, 0.31622777f},
  {850, 20, 10,  5, 1, 1, 10, 0, 0.31622777f},
  {950, 20, 45,  5, 1, 1,  5, 1, 0.31622777f},
  {1000,35, 45,  5, 1, 0,  5, 1, 0.31622777f},
  {1050,35,  0,  5, 1, 1, 10, 0, 0.31622777f},
  {1150,35, 20,  5, 1, 1, 10, 0, 0.31622777f},
  {1250,35, 30,  5, 1, 1,  5, 1, 0.31622777f},
  {0,    0, 1, 10, 0, 0, 6, 0, 0.22360680f},
  {120, 10, 0, 10, 0, 0, 1, 0, 0.22360680f},
  {140, 20, 0,  5, 1, 1, 1, 0, 0.31622777f},
  {150, 35, 1,  5, 1, 1, 6, 0, 0.31622777f},
};

// norm = 1/sqrt(m1)
__device__ __constant__ LinPath g_lin[9] = {
  {0,  0,  0, 1, 0, 10, 1.0f},
  {10, 0, 20, 1, 0, 10, 1.0f},
  {0,   0,  0, 10, 0, 10, 0.31622777f},
  {100, 0, 20, 10, 0, 10, 0.31622777f},
  {200,10, 10, 10, 0, 10, 0.31622777f},
  {300,20, 30,  5, 1,  5, 0.44721360f},
  {325,35, 45,  5, 1,  5, 0.44721360f},
  {0,  0, 1, 10, 0, 6, 0.31622777f},
  {60,10, 0, 10, 0, 1, 0.31622777f},
};

__device__ inline float sus_f(float t) { return t > 0.f ? __expf(-1.f / t) : 0.f; }

__global__ void build_tp_kernel(const float* __restrict__ tw, float* __restrict__ kbuf,
                                int CIN, int COUT, int path_base) {
  TpPath p = g_tp[path_base + blockIdx.x];
  const int dl1 = 2 * p.l1 + 1, dlo = 2 * p.lo + 1;
  const int du = p.m1 * dl1, dw = p.mo * dlo;
  const int total = 125 * du * dw;
  const float C0 = 1.14136f * expf(2.0f);
  for (int e = threadIdx.x; e < total; e += blockDim.x) {
    int xyz = e / (du * dw);
    int rem = e % (du * dw);
    int ui = rem / dw, wk = rem % dw;
    int u = ui / dl1, i = ui % dl1;
    int w = wk / dlo, kk = wk % dlo;
    int kx = xyz / 25, ky = (xyz / 5) % 5, kz = xyz % 5;
    float cx = (float)(kx - 2), cy = (float)(ky - 2), cz = (float)(kz - 2);
    float d = sqrtf(cx * cx + cy * cy + cz * cz);
    float t = 1.2f * d;
    float e0 = C0 * sus_f(t) * sus_f(2.f - t);
    float e1 = C0 * sus_f(t - 1.f) * sus_f(3.f - t);
    float radial = e0 * tw[p.off + (0 * p.m1 + u) * p.mo + w] +
                   e1 * tw[p.off + (1 * p.m1 + u) * p.mo + w];
    float invd = (d > 0.f) ? 1.f / d : 0.f;
    const float s3 = 1.7320508f;
    float sh1[3] = { s3 * cy * invd, s3 * cz * invd, s3 * cx * invd };
    float shfac;
    if (p.l1 == 0 && p.i2 == 0)      shfac = 1.f;
    else if (p.l1 == 0)              shfac = sh1[kk];
    else if (p.i2 == 0)              shfac = (i == kk) ? 1.f : 0.f;
    else if (p.lo == 0)              shfac = sh1[i] * 0.57735027f;
    else {
      if (i == kk) shfac = 0.f;
      else {
        int j = 3 - i - kk;
        float sgn = (j == (i + 1) % 3) ? 1.f : -1.f;
        shfac = sgn * sh1[j] * 0.70710678f;
      }
    }
    kbuf[(size_t)(xyz * CIN + p.ci + ui) * COUT + p.co + wk] = p.alpha * radial * shfac;
  }
}

__global__ void set_center_kernel(const float* __restrict__ lw, float* __restrict__ kbuf,
                                  int CIN, int COUT, int lin_base, int nlin) {
  for (int l = 0; l < nlin; l++) {
    LinPath q = g_lin[lin_base + l];
    int dl = 2 * q.l + 1;
    int tot = q.m1 * q.mo * dl;
    for (int e = threadIdx.x; e < tot; e += blockDim.x) {
      int u = e / (q.mo * dl);
      int r = e % (q.mo * dl);
      int w = r / dl, ii = r % dl;
      kbuf[(size_t)(62 * CIN + q.ci + u * dl + ii) * COUT + q.co + w * dl + ii] =
          q.norm * lw[q.off + u * q.mo + w];
    }
  }
}

// fp32 kbuf [125][CIN][COUT] -> bf16 kwbT [125][64 co][64 ci], zero-padded
__global__ void convert_w(const float* __restrict__ kbuf, unsigned short* __restrict__ kwbT,
                          int CIN, int COUT) {
  int idx = blockIdx.x * 256 + threadIdx.x;
  if (idx >= 125 * 64 * 64) return;
  int tap = idx >> 12, co = (idx >> 6) & 63, ci = idx & 63;
  float v = (ci < CIN && co < COUT) ? kbuf[((size_t)tap * CIN + ci) * COUT + co] : 0.f;
  __hip_bfloat16 h = __float2bfloat16(v);
  kwbT[idx] = *(unsigned short*)&h;
}

// layer-0 tap-packed B: [5 dxi][2 mf][64 co][32 k] bf16.
__global__ void build_w0(const float* __restrict__ k0, unsigned short* __restrict__ wb0L) {
  int idx = blockIdx.x * 256 + threadIdx.x;
  if (idx >= 5 * 2 * 64 * 32) return;
  int k = idx & 31, co = (idx >> 5) & 63, mf = (idx >> 11) & 1, dxi = idx >> 12;
  float v = 0.f;
  if (co < 60) {
    if (mf == 0) {
      int dy = k >> 3, dz = k & 7;
      if (dz < 5) v = k0[(size_t)(((dxi * 5 + dy) * 5 + dz)) * 60 + co];
    } else {
      int kg = k >> 3, dz = k & 7;
      if (kg == 0 && dz < 5) v = k0[(size_t)(((dxi * 5 + 4) * 5 + dz)) * 60 + co];
    }
  }
  __hip_bfloat16 h = __float2bfloat16(v);
  wb0L[idx] = *(unsigned short*)&h;
}

__device__ inline float gelu_f(float x) {
  float inner = 0.79788456f * (x + 0.044715f * x * x * x);
  return 0.5f * x * (1.f + tanhf(inner));
}
__device__ inline float sigm_f(float x) { return 1.f / (1.f + __expf(-x)); }

// Gate for one 16-z tile from a [64 co][16 z] fp32 LDS tile -> packed 64-ch
// bf16 output dwords at myO. Caller handles barriers/copy.
__device__ inline void gate_tile(const float* my, unsigned int* myO, int z) {
#pragma unroll
  for (int p = 0; p < 25; p++) {            // out channel pair (2p, 2p+1)
    float a0, a1;
    if (p < 5) {
      a0 = gelu_f(my[(2 * p) * 16 + z]);
      a1 = gelu_f(my[(2 * p + 1) * 16 + z]);
    } else if (p < 10) {
      a0 = tanhf(my[(2 * p) * 16 + z]);
      a1 = tanhf(my[(2 * p + 1) * 16 + z]);
    } else {
      int q0 = 2 * (p - 10), q1 = q0 + 1;
      a0 = my[(30 + q0) * 16 + z] * sigm_f(my[(20 + q0 / 3) * 16 + z]);
      a1 = my[(30 + q1) * 16 + z] * sigm_f(my[(20 + q1 / 3) * 16 + z]);
    }
    __hip_bfloat162 p2;
    p2.x = __float2bfloat16(a0);
    p2.y = __float2bfloat16(a1);
    myO[z * 32 + p] = *(unsigned int*)&p2;
  }
#pragma unroll
  for (int p = 25; p < 32; p++) myO[z * 32 + p] = 0u;   // ch pad 50..63
}

// Full-acc epilogue used by conv0 (4-wave kernel): acc[3][NT] covers all co.
template <int NT>
__device__ inline void epilogue_gate(f32x4 (&acc)[3][NT], float* my,
                                     unsigned short* out_, int n, int x, int y,
                                     int l, int lm, int kg) {
  unsigned int* myO = (unsigned int*)(my + 1024);
#pragma unroll
  for (int zt = 0; zt < 3; zt++) {
#pragma unroll
    for (int nt = 0; nt < NT; nt++)
      *(f32x4*)(my + (lm + 16 * nt) * 16 + 4 * kg) = acc[zt][nt];
    if (l < 16) gate_tile(my, myO, l);
    unsigned int* gout = (unsigned int*)out_ +
        ((size_t)(((n * 48 + x) * 48 + y) * 48 + 16 * zt)) * 32;
#pragma unroll 1
    for (int e = l; e < 512; e += 64) gout[e] = myO[e];
  }
}

// MFMA implicit-GEMM conv, co-split 512-thr blocks. Wave w: y-pair (w&3)
// (rows 2wp,2wp+1), co-half (w>>2). Staging/A-path identical to round 12.
// MODE 0: paired-wave gate -> 64-pad bf16 out. MODE 1: global sum -> f32.
template <int CIN, int COUT, int MODE>
__global__ __launch_bounds__(512, 2)
void conv_mfma(const unsigned short* __restrict__ act, const short* __restrict__ kwbT,
               void* __restrict__ out_) {
  constexpr int NTH = (MODE == 0) ? 2 : 1;  // co tiles per wave (half-split)
  constexpr int KC = (CIN + 31) / 32;       // K chunks of 32
  // [12 yin][48 zin][64 ci] bf16, swizzled dwords: 73728 B; epilogue aliases.
  __shared__ __align__(16) unsigned int Albs[12 * 48 * 32];

  const int tid = threadIdx.x;
  const int l = tid & 63;
  const int w = tid >> 6;        // wave 0..7
  const int wp = w & 3;          // y-pair: rows {2wp, 2wp+1}
  const int ch = w >> 2;         // co half (MODE 0)
  const int lm = l & 15;
  const int kg = l >> 4;
  const int co_off = (MODE == 0) ? ch * 32 : 0;

  const int bid = blockIdx.x;
  const int yb = bid % 6;
  const int x = (bid / 6) % 48;
  const int n = bid / (6 * 48);

  f32x4 acc[2][3][NTH];
#pragma unroll
  for (int yy = 0; yy < 2; yy++)
#pragma unroll
    for (int zt = 0; zt < 3; zt++)
#pragma unroll
      for (int nt = 0; nt < NTH; nt++) acc[yy][zt][nt] = (f32x4){0.f, 0.f, 0.f, 0.f};

  for (int dxi = 0; dxi < 5; dxi++) {
    int xin = x + dxi - 2;
    if (xin < 0 || xin >= 48) continue;        // block-uniform
    __syncthreads();                            // prior tap-loop done with Albs
    // ---- stage plane (xin): [12 yin][48 zin][64 ci] bf16, swizzled ----
    for (int e = tid; e < 12 * 48 * 32; e += 512) {
      int yi = e / (48 * 32);
      int rem = e % (48 * 32);
      int zin = rem / 32, pi = rem % 32;
      int yin = 8 * yb + yi - 2;
      unsigned int val = 0;
      if (yin >= 0 && yin < 48) {
        const unsigned short* p = act +
            ((size_t)((n * 48 + xin) * 48 + yin) * 48 + zin) * 64 + 2 * pi;
        val = *(const unsigned int*)p;          // two bf16 (64-ch padded)
      }
      int u = pi >> 2, j = pi & 3;
      Albs[(yi * 48 + zin) * 32 + ((((u ^ (zin & 7)) << 2) | j))] = val;
    }
    __syncthreads();

    if (MODE == 0 || w < 4) {                   // layer-4: waves 4-7 idle
      const short* Albs_s = (const short*)Albs;
#pragma unroll 1
      for (int dy = 0; dy < 5; dy++) {
        const int tapbase = (dxi * 5 + dy) * 5;
#pragma unroll
        for (int dz = 0; dz < 5; dz++) {
          // ---- B fragments for this tap (co-half) ----
          bf16x8 bfr[NTH * KC];
          {
            const short* wb_ = kwbT + ((size_t)(tapbase + dz) << 12) +
                               (co_off + lm) * 64 + kg * 8;
#pragma unroll
            for (int nt = 0; nt < NTH; nt++)
#pragma unroll
              for (int kc = 0; kc < KC; kc++)
                bfr[nt * KC + kc] = *(const bf16x8*)(wb_ + nt * 1024 + kc * 32);
          }
          // ---- A fragments (LDS), z-edge lanes zeroed in registers ----
          bf16x8 afr[2][3][KC];
#pragma unroll
          for (int zt = 0; zt < 3; zt++) {
            const int zraw = 16 * zt + lm + dz - 2;
            const int zc = min(max(zraw, 0), 47);
            const bool zval = (zraw >= 0) && (zraw < 48);
#pragma unroll
            for (int yy = 0; yy < 2; yy++) {
              const int yrow = 2 * wp + yy + dy;     // 0..11
              const int rowoff = (yrow * 48 + zc) * 64;
#pragma unroll
              for (int kc = 0; kc < KC; kc++) {
                int u = (4 * kc + kg) ^ (zc & 7);
                bf16x8 v = *(const bf16x8*)(Albs_s + rowoff + u * 8);
                afr[yy][zt][kc] = zval ? v : (bf16x8)(short)0;
              }
            }
          }
          // ---- 24 MFMAs (NTH=2) ----
#pragma unroll
          for (int yy = 0; yy < 2; yy++)
#pragma unroll
            for (int zt = 0; zt < 3; zt++)
#pragma unroll
              for (int nt = 0; nt < NTH; nt++)
#pragma unroll
                for (int kc = 0; kc < KC; kc++)
                  acc[yy][zt][nt] = __builtin_amdgcn_mfma_f32_16x16x32_bf16(
                      afr[yy][zt][kc], bfr[nt * KC + kc], acc[yy][zt][nt], 0, 0, 0);
        }
      }
    }
  }

  if constexpr (MODE == 0) {
    __syncthreads();                            // all waves done reading Albs
    float* base = (float*)Albs;                 // 2 x (4 pairs x 1536 f) alias
    int par = 0;
#pragma unroll
    for (int yy = 0; yy < 2; yy++) {
#pragma unroll
      for (int zt = 0; zt < 3; zt++) {
        float* my = base + par * 6144 + wp * 1536;
        unsigned int* myO = (unsigned int*)(my + 1024);
        // both co-half waves write their quadrants (static acc idx)
#pragma unroll
        for (int nt = 0; nt < NTH; nt++)
          *(f32x4*)(my + (co_off + lm + 16 * nt) * 16 + 4 * kg) = acc[yy][zt][nt];
        __syncthreads();
        if (ch == 0 && l < 16) gate_tile(my, myO, l);
        __syncthreads();
        // paired copy: each wave moves 256 contiguous dwords
        unsigned int* gout = (unsigned int*)out_ +
            ((size_t)(((n * 48 + x) * 48 + (8 * yb + 2 * wp + yy)) * 48 + 16 * zt)) * 32;
#pragma unroll
        for (int q = 0; q < 4; q++)
          gout[ch * 256 + q * 64 + l] = myO[ch * 256 + q * 64 + l];
        par ^= 1;
      }
    }
  } else {
    // layer 4: channel co=lm lives in lanes {lm, lm+16, lm+32, lm+48}
    if (w < 4) {
      float s = 0.f;
#pragma unroll
      for (int yy = 0; yy < 2; yy++)
#pragma unroll
        for (int zt = 0; zt < 3; zt++)
#pragma unroll
          for (int r = 0; r < 4; r++) s += acc[yy][zt][0][r];
      s += __shfl_xor(s, 16);
      s += __shfl_xor(s, 32);
      if (l < 7) atomicAdd(&((float*)out_)[n * 7 + l], s);
    }
  }
}

// Layer 0 (CIN=1): taps packed into MFMA-K (round-7 structure; writes the
// 64-ch padded activation layout via the shared epilogue).
__global__ __launch_bounds__(256, 4)
void conv0_mfma(const float* __restrict__ in_, const short* __restrict__ wb0L,
                unsigned short* __restrict__ out_) {
  __shared__ float A0[8 * 72];                 // [yi][zz] fp32, zz 52..71 = 0
  __shared__ __align__(16) float outbuf0[4 * 1536];

  const int tid = threadIdx.x;
  const int l = tid & 63;
  const int w = tid >> 6;
  const int lm = l & 15;
  const int kg = l >> 4;
  const int yb = blockIdx.x % 12;
  const int x = (blockIdx.x / 12) % 48;
  const int n = blockIdx.x / (12 * 48);

  f32x4 acc[3][4];
#pragma unroll
  for (int zt = 0; zt < 3; zt++)
#pragma unroll
    for (int nt = 0; nt < 4; nt++) acc[zt][nt] = (f32x4){0.f, 0.f, 0.f, 0.f};

  for (int dxi = 0; dxi < 5; dxi++) {
    int xin = x + dxi - 2;
    if (xin < 0 || xin >= 48) continue;
    __syncthreads();
    for (int e = tid; e < 8 * 72; e += 256) {
      int yi = e / 72, zz = e % 72;
      int yin = 4 * yb + yi - 2, zin = zz - 2;
      A0[e] = (yin >= 0 && yin < 48 && zin >= 0 && zin < 48)
                  ? in_[(size_t)((n * 48 + xin) * 48 + yin) * 48 + zin] : 0.f;
    }
    __syncthreads();
#pragma unroll
    for (int mf = 0; mf < 2; mf++) {
      const short* wbp = wb0L + ((size_t)(dxi * 2 + mf) * 64 + lm) * 32 + kg * 8;
      bf16x8 bfr[4];
#pragma unroll
      for (int nt = 0; nt < 4; nt++) bfr[nt] = *(const bf16x8*)(wbp + nt * 16 * 32);
      const int row = mf ? (w + 4) : (w + kg);
#pragma unroll
      for (int zt = 0; zt < 3; zt++) {
        const float* ap = A0 + row * 72 + 16 * zt + lm;
        union { bf16x8 v; unsigned short s[8]; } af;
#pragma unroll
        for (int j = 0; j < 8; j++) {
          __hip_bfloat16 h = __float2bfloat16(ap[j]);
          af.s[j] = *(unsigned short*)&h;
        }
#pragma unroll
        for (int nt = 0; nt < 4; nt++)
          acc[zt][nt] = __builtin_amdgcn_mfma_f32_16x16x32_bf16(
              af.v, bfr[nt], acc[zt][nt], 0, 0, 0);
      }
    }
  }

  float* my = outbuf0 + w * 1536;
  epilogue_gate<4>(acc, my, out_, n, x, 4 * yb + w, l, lm, kg);
}

extern "C" void kernel_launch(void* const* d_in, const int* in_sizes, int n_in,
                              void* d_out, int out_size, void* d_ws, size_t ws_size,
                              hipStream_t stream) {
  // setup_inputs() dict order (INTERLEAVED): x, tp_w0, lin_w0, tp_w1, lin_w1, ...
  const float* x   = (const float*)d_in[0];
  const float* tw0 = (const float*)d_in[1];
  const float* lw0 = (const float*)d_in[2];
  const float* tw1 = (const float*)d_in[3];
  const float* lw1 = (const float*)d_in[4];
  const float* tw2 = (const float*)d_in[5];
  const float* lw2 = (const float*)d_in[6];
  const float* tw3 = (const float*)d_in[7];
  const float* lw3 = (const float*)d_in[8];
  const float* tw4 = (const float*)d_in[9];
  const float* lw4 = (const float*)d_in[10];

  float* ws = (float*)d_ws;
  float* k0 = ws;                 // 125*1*60   = 7500
  float* k1 = k0 + 7500;          // 125*50*60  = 375000
  float* k2 = k1 + 375000;
  float* k3 = k2 + 375000;
  float* k4 = k3 + 375000;        // 125*50*7   = 43750  (end: 1,176,250)
  // 64-ch-padded bf16 activations: 2*48^3*64 = 14,155,776 ushorts each
  unsigned short* actA = (unsigned short*)(ws + 1200000);
  unsigned short* actB = actA + 14155776;     // ends float offset 15,355,776
  // bf16 transposed weights [125][64][64] per layer
  unsigned short* wb1 = (unsigned short*)(ws + 15360000);
  unsigned short* wb2 = wb1 + 512000;
  unsigned short* wb3 = wb2 + 512000;
  unsigned short* wb4 = wb3 + 512000;
  unsigned short* wb0L = wb4 + 512000;        // [5][2][64][32] = 20480

  hipMemsetAsync(ws, 0, (size_t)1176250 * sizeof(float), stream);
  hipMemsetAsync(d_out, 0, (size_t)out_size * sizeof(float), stream);

  build_tp_kernel<<<3, 128, 0, stream>>>(tw0, k0, 1, 60, 0);
  build_tp_kernel<<<12, 128, 0, stream>>>(tw1, k1, 50, 60, 3);
  build_tp_kernel<<<12, 128, 0, stream>>>(tw2, k2, 50, 60, 3);
  build_tp_kernel<<<12, 128, 0, stream>>>(tw3, k3, 50, 60, 3);
  build_tp_kernel<<<4, 128, 0, stream>>>(tw4, k4, 50, 7, 15);
  set_center_kernel<<<1, 256, 0, stream>>>(lw0, k0, 1, 60, 0, 2);
  set_center_kernel<<<1, 256, 0, stream>>>(lw1, k1, 50, 60, 2, 5);
  set_center_kernel<<<1, 256, 0, stream>>>(lw2, k2, 50, 60, 2, 5);
  set_center_kernel<<<1, 256, 0, stream>>>(lw3, k3, 50, 60, 2, 5);
  set_center_kernel<<<1, 256, 0, stream>>>(lw4, k4, 50, 7, 7, 2);

  convert_w<<<2000, 256, 0, stream>>>(k1, wb1, 50, 60);
  convert_w<<<2000, 256, 0, stream>>>(k2, wb2, 50, 60);
  convert_w<<<2000, 256, 0, stream>>>(k3, wb3, 50, 60);
  convert_w<<<2000, 256, 0, stream>>>(k4, wb4, 50, 7);
  build_w0<<<80, 256, 0, stream>>>(k0, wb0L);

  const int grid0 = 2 * 48 * 12;  // conv0: (n, x, y-quad), 1 y per wave
  const int grid  = 2 * 48 * 6;   // mid/last: (n, x, y-octant), 512 thr
  conv0_mfma<<<grid0, 256, 0, stream>>>(x, (const short*)wb0L, actA);
  conv_mfma<50, 60, 0><<<grid, 512, 0, stream>>>(actA, (const short*)wb1, actB);
  conv_mfma<50, 60, 0><<<grid, 512, 0, stream>>>(actB, (const short*)wb2, actA);
  conv_mfma<50, 60, 0><<<grid, 512, 0, stream>>>(actA, (const short*)wb3, actB);
  conv_mfma<50, 7, 1><<<grid, 512, 0, stream>>>(actB, (const short*)wb4, d_out);
}

// Round 18
// 1986.554 us; speedup vs baseline: 2.1552x; 1.1451x over previous
//
#include <hip/hip_runtime.h>
#include <hip/hip_bf16.h>
#include <math.h>

// ---------------------------------------------------------------------------
// Equivariant 3D CNN (e3nn-style), 5 layers, 48^3 grid, batch 2.
// Round-18: r17 structure (co-split 512-thr, 8y x 48z, 2 waves/SIMD) plus:
//  1) 16B staging: 9 precomputed units/thread -> 9 dwordx4 + 9 ds_write_b128
//     (was 36 scalar pairs), swizzle applied at unit level.
//  2) Async-STAGE (T14): prefetch next plane's 9 regs after the write
//     barrier; HBM latency hides under current plane's compute.
//  3) Epilogue conflict fixes: acc-store swizzle (kg^(lm&3)) 16->4-way;
//     gate-out swizzle (p^z) 16-way->0; unswizzled in the coalesced copy.
// Evidence: r17 7.96M conflicts localized to epilogue stores; staging was
// 36 scalar load/write pairs on the barrier-critical path each plane.
// ---------------------------------------------------------------------------

typedef __attribute__((ext_vector_type(8))) short bf16x8;
typedef __attribute__((ext_vector_type(4))) float f32x4;
typedef __attribute__((ext_vector_type(4))) unsigned int u32x4;

struct TpPath { int off, ci, co, m1, l1, i2, mo, lo; float alpha; };
struct LinPath { int off, ci, co, m1, l, mo; float norm; };

// alpha = 1/sqrt(m1*1*R_BASIS)
__device__ __constant__ TpPath g_tp[19] = {
  {0,  0,  0, 1, 0, 0, 10, 0, 0.70710678f},
  {20, 0, 20, 1, 0, 0, 10, 0, 0.70710678f},
  {40, 0, 45, 1, 0, 1,  5, 1, 0.70710678f},
  {0,    0,  0, 10, 0, 0, 10, 0, 0.22360680f},
  {200,  0, 20, 10, 0, 0, 10, 0, 0.22360680f},
  {400,  0, 45, 10, 0, 1,  5, 1, 0.22360680f},
  {500, 10, 10, 10, 0, 0, 10, 0, 0.22360680f},
  {700, 10, 30, 10, 0, 1,  5, 1, 0.22360680f},
  {800, 20, 30,  5, 1, 0,  5, 1, 0.31622777f},
  {850, 20, 10,  5, 1, 1, 10, 0, 0.31622777f},
  {950, 20, 45,  5, 1, 1,  5, 1, 0.31622777f},
  {1000,35, 45,  5, 1, 0,  5, 1, 0.31622777f},
  {1050,35,  0,  5, 1, 1, 10, 0, 0.31622777f},
  {1150,35, 20,  5, 1, 1, 10, 0, 0.31622777f},
  {1250,35, 30,  5, 1, 1,  5, 1, 0.31622777f},
  {0,    0, 1, 10, 0, 0, 6, 0, 0.22360680f},
  {120, 10, 0, 10, 0, 0, 1, 0, 0.22360680f},
  {140, 20, 0,  5, 1, 1, 1, 0, 0.31622777f},
  {150, 35, 1,  5, 1, 1, 6, 0, 0.31622777f},
};

// norm = 1/sqrt(m1)
__device__ __constant__ LinPath g_lin[9] = {
  {0,  0,  0, 1, 0, 10, 1.0f},
  {10, 0, 20, 1, 0, 10, 1.0f},
  {0,   0,  0, 10, 0, 10, 0.31622777f},
  {100, 0, 20, 10, 0, 10, 0.31622777f},
  {200,10, 10, 10, 0, 10, 0.31622777f},
  {300,20, 30,  5, 1,  5, 0.44721360f},
  {325,35, 45,  5, 1,  5, 0.44721360f},
  {0,  0, 1, 10, 0, 6, 0.31622777f},
  {60,10, 0, 10, 0, 1, 0.31622777f},
};

__device__ inline float sus_f(float t) { return t > 0.f ? __expf(-1.f / t) : 0.f; }

__global__ void build_tp_kernel(const float* __restrict__ tw, float* __restrict__ kbuf,
                                int CIN, int COUT, int path_base) {
  TpPath p = g_tp[path_base + blockIdx.x];
  const int dl1 = 2 * p.l1 + 1, dlo = 2 * p.lo + 1;
  const int du = p.m1 * dl1, dw = p.mo * dlo;
  const int total = 125 * du * dw;
  const float C0 = 1.14136f * expf(2.0f);
  for (int e = threadIdx.x; e < total; e += blockDim.x) {
    int xyz = e / (du * dw);
    int rem = e % (du * dw);
    int ui = rem / dw, wk = rem % dw;
    int u = ui / dl1, i = ui % dl1;
    int w = wk / dlo, kk = wk % dlo;
    int kx = xyz / 25, ky = (xyz / 5) % 5, kz = xyz % 5;
    float cx = (float)(kx - 2), cy = (float)(ky - 2), cz = (float)(kz - 2);
    float d = sqrtf(cx * cx + cy * cy + cz * cz);
    float t = 1.2f * d;
    float e0 = C0 * sus_f(t) * sus_f(2.f - t);
    float e1 = C0 * sus_f(t - 1.f) * sus_f(3.f - t);
    float radial = e0 * tw[p.off + (0 * p.m1 + u) * p.mo + w] +
                   e1 * tw[p.off + (1 * p.m1 + u) * p.mo + w];
    float invd = (d > 0.f) ? 1.f / d : 0.f;
    const float s3 = 1.7320508f;
    float sh1[3] = { s3 * cy * invd, s3 * cz * invd, s3 * cx * invd };
    float shfac;
    if (p.l1 == 0 && p.i2 == 0)      shfac = 1.f;
    else if (p.l1 == 0)              shfac = sh1[kk];
    else if (p.i2 == 0)              shfac = (i == kk) ? 1.f : 0.f;
    else if (p.lo == 0)              shfac = sh1[i] * 0.57735027f;
    else {
      if (i == kk) shfac = 0.f;
      else {
        int j = 3 - i - kk;
        float sgn = (j == (i + 1) % 3) ? 1.f : -1.f;
        shfac = sgn * sh1[j] * 0.70710678f;
      }
    }
    kbuf[(size_t)(xyz * CIN + p.ci + ui) * COUT + p.co + wk] = p.alpha * radial * shfac;
  }
}

__global__ void set_center_kernel(const float* __restrict__ lw, float* __restrict__ kbuf,
                                  int CIN, int COUT, int lin_base, int nlin) {
  for (int l = 0; l < nlin; l++) {
    LinPath q = g_lin[lin_base + l];
    int dl = 2 * q.l + 1;
    int tot = q.m1 * q.mo * dl;
    for (int e = threadIdx.x; e < tot; e += blockDim.x) {
      int u = e / (q.mo * dl);
      int r = e % (q.mo * dl);
      int w = r / dl, ii = r % dl;
      kbuf[(size_t)(62 * CIN + q.ci + u * dl + ii) * COUT + q.co + w * dl + ii] =
          q.norm * lw[q.off + u * q.mo + w];
    }
  }
}

// fp32 kbuf [125][CIN][COUT] -> bf16 kwbT [125][64 co][64 ci], zero-padded
__global__ void convert_w(const float* __restrict__ kbuf, unsigned short* __restrict__ kwbT,
                          int CIN, int COUT) {
  int idx = blockIdx.x * 256 + threadIdx.x;
  if (idx >= 125 * 64 * 64) return;
  int tap = idx >> 12, co = (idx >> 6) & 63, ci = idx & 63;
  float v = (ci < CIN && co < COUT) ? kbuf[((size_t)tap * CIN + ci) * COUT + co] : 0.f;
  __hip_bfloat16 h = __float2bfloat16(v);
  kwbT[idx] = *(unsigned short*)&h;
}

// layer-0 tap-packed B: [5 dxi][2 mf][64 co][32 k] bf16.
__global__ void build_w0(const float* __restrict__ k0, unsigned short* __restrict__ wb0L) {
  int idx = blockIdx.x * 256 + threadIdx.x;
  if (idx >= 5 * 2 * 64 * 32) return;
  int k = idx & 31, co = (idx >> 5) & 63, mf = (idx >> 11) & 1, dxi = idx >> 12;
  float v = 0.f;
  if (co < 60) {
    if (mf == 0) {
      int dy = k >> 3, dz = k & 7;
      if (dz < 5) v = k0[(size_t)(((dxi * 5 + dy) * 5 + dz)) * 60 + co];
    } else {
      int kg = k >> 3, dz = k & 7;
      if (kg == 0 && dz < 5) v = k0[(size_t)(((dxi * 5 + 4) * 5 + dz)) * 60 + co];
    }
  }
  __hip_bfloat16 h = __float2bfloat16(v);
  wb0L[idx] = *(unsigned short*)&h;
}

__device__ inline float gelu_f(float x) {
  float inner = 0.79788456f * (x + 0.044715f * x * x * x);
  return 0.5f * x * (1.f + tanhf(inner));
}
__device__ inline float sigm_f(float x) { return 1.f / (1.f + __expf(-x)); }

// Swizzled element index in the [64 co][16 z] fp32 acc tile: z-quad XOR'd
// with (c&3) so the f32x4 acc store is 4-way instead of 16-way conflicted.
__device__ inline int eidx(int c, int z) {
  return c * 16 + ((((z >> 2) ^ (c & 3)) << 2) | (z & 3));
}
// Swizzled packed-out dword index: channel-pair p XOR z -> conflict-free.
__device__ inline int oidx(int z, int p) { return z * 32 + (p ^ z); }
// Inverse for the coalesced copy: out dword e -> myO index.
__device__ inline int uidx(int e) {
  return (e & ~31) | ((e & 31) ^ ((e >> 5) & 15));
}

// Gate for one 16-z tile from swizzled acc tile -> swizzled packed dwords.
__device__ inline void gate_tile(const float* my, unsigned int* myO, int z) {
#pragma unroll
  for (int p = 0; p < 25; p++) {            // out channel pair (2p, 2p+1)
    float a0, a1;
    if (p < 5) {
      a0 = gelu_f(my[eidx(2 * p, z)]);
      a1 = gelu_f(my[eidx(2 * p + 1, z)]);
    } else if (p < 10) {
      a0 = tanhf(my[eidx(2 * p, z)]);
      a1 = tanhf(my[eidx(2 * p + 1, z)]);
    } else {
      int q0 = 2 * (p - 10), q1 = q0 + 1;
      a0 = my[eidx(30 + q0, z)] * sigm_f(my[eidx(20 + q0 / 3, z)]);
      a1 = my[eidx(30 + q1, z)] * sigm_f(my[eidx(20 + q1 / 3, z)]);
    }
    __hip_bfloat162 p2;
    p2.x = __float2bfloat16(a0);
    p2.y = __float2bfloat16(a1);
    myO[oidx(z, p)] = *(unsigned int*)&p2;
  }
#pragma unroll
  for (int p = 25; p < 32; p++) myO[oidx(z, p)] = 0u;   // ch pad 50..63
}

// Full-acc epilogue used by conv0 (4-wave kernel): acc[3][NT] covers all co.
template <int NT>
__device__ inline void epilogue_gate(f32x4 (&acc)[3][NT], float* my,
                                     unsigned short* out_, int n, int x, int y,
                                     int l, int lm, int kg) {
  unsigned int* myO = (unsigned int*)(my + 1024);
#pragma unroll
  for (int zt = 0; zt < 3; zt++) {
#pragma unroll
    for (int nt = 0; nt < NT; nt++)
      *(f32x4*)(my + (lm + 16 * nt) * 16 + ((kg ^ (lm & 3)) << 2)) = acc[zt][nt];
    if (l < 16) gate_tile(my, myO, l);
    unsigned int* gout = (unsigned int*)out_ +
        ((size_t)(((n * 48 + x) * 48 + y) * 48 + 16 * zt)) * 32;
#pragma unroll 1
    for (int e = l; e < 512; e += 64) gout[e] = myO[uidx(e)];
  }
}

// MFMA implicit-GEMM conv, co-split 512-thr blocks. Wave w: y-pair (w&3),
// co-half (w>>2). 16B async staging + swizzled epilogue (round 18).
// MODE 0: paired-wave gate -> 64-pad bf16 out. MODE 1: global sum -> f32.
template <int CIN, int COUT, int MODE>
__global__ __launch_bounds__(512, 2)
void conv_mfma(const unsigned short* __restrict__ act, const short* __restrict__ kwbT,
               void* __restrict__ out_) {
  constexpr int NTH = (MODE == 0) ? 2 : 1;  // co tiles per wave (half-split)
  constexpr int KC = (CIN + 31) / 32;       // K chunks of 32
  // [12 yin][48 zin][64 ci] bf16, swizzled dwords: 73728 B; epilogue aliases.
  __shared__ __align__(16) unsigned int Albs[12 * 48 * 32];

  const int tid = threadIdx.x;
  const int l = tid & 63;
  const int w = tid >> 6;        // wave 0..7
  const int wp = w & 3;          // y-pair: rows {2wp, 2wp+1}
  const int ch = w >> 2;         // co half (MODE 0)
  const int lm = l & 15;
  const int kg = l >> 4;
  const int co_off = (MODE == 0) ? ch * 32 : 0;

  const int bid = blockIdx.x;
  const int yb = bid % 6;
  const int x = (bid / 6) % 48;
  const int n = bid / (6 * 48);

  // ---- per-thread staging slots: 9 x 16B units (4608 = 9*512 exactly) ----
  int g_off[9]; bool g_ok[9]; int l_off[9];
#pragma unroll
  for (int i = 0; i < 9; i++) {
    int e = tid + i * 512;
    int yi = e / 384;                 // 48*8 units per y row
    int rem = e % 384;
    int zin = rem >> 3, u = rem & 7;
    int yin = 8 * yb + yi - 2;
    g_ok[i] = (yin >= 0) && (yin < 48);
    int yc = min(max(yin, 0), 47);
    g_off[i] = (yc * 48 + zin) * 64 + u * 8;                  // ushort units
    l_off[i] = (yi * 48 + zin) * 32 + ((u ^ (zin & 7)) << 2); // dword units
  }

  f32x4 acc[2][3][NTH];
#pragma unroll
  for (int yy = 0; yy < 2; yy++)
#pragma unroll
    for (int zt = 0; zt < 3; zt++)
#pragma unroll
      for (int nt = 0; nt < NTH; nt++) acc[yy][zt][nt] = (f32x4){0.f, 0.f, 0.f, 0.f};

  u32x4 rg[9];
  const int xlo = max(x - 2, 0), xhi = min(x + 2, 47);

#define LOADP(xin_)                                                            \
  {                                                                            \
    const unsigned short* pb = act + (size_t)((n * 48 + (xin_)) * 2304) * 64;  \
    _Pragma("unroll")                                                          \
    for (int i = 0; i < 9; i++)                                                \
      rg[i] = g_ok[i] ? *(const u32x4*)(pb + g_off[i])                         \
                      : (u32x4){0u, 0u, 0u, 0u};                               \
  }

  LOADP(xlo);
#pragma unroll 1
  for (int xin = xlo; xin <= xhi; ++xin) {
    __syncthreads();                            // prior compute done with Albs
#pragma unroll
    for (int i = 0; i < 9; i++)                 // 9 x ds_write_b128
      *(u32x4*)((unsigned int*)Albs + l_off[i]) = rg[i];
    __syncthreads();                            // staging visible
    if (xin < xhi) LOADP(xin + 1);              // prefetch next plane (T14)

    if (MODE == 0 || w < 4) {                   // layer-4: waves 4-7 idle
      const int dxi = xin - x + 2;
      const short* Albs_s = (const short*)Albs;
#pragma unroll 1
      for (int dy = 0; dy < 5; dy++) {
        const int tapbase = (dxi * 5 + dy) * 5;
#pragma unroll
        for (int dz = 0; dz < 5; dz++) {
          // ---- B fragments for this tap (co-half) ----
          bf16x8 bfr[NTH * KC];
          {
            const short* wb_ = kwbT + ((size_t)(tapbase + dz) << 12) +
                               (co_off + lm) * 64 + kg * 8;
#pragma unroll
            for (int nt = 0; nt < NTH; nt++)
#pragma unroll
              for (int kc = 0; kc < KC; kc++)
                bfr[nt * KC + kc] = *(const bf16x8*)(wb_ + nt * 1024 + kc * 32);
          }
          // ---- A fragments (LDS), z-edge lanes zeroed in registers ----
          bf16x8 afr[2][3][KC];
#pragma unroll
          for (int zt = 0; zt < 3; zt++) {
            const int zraw = 16 * zt + lm + dz - 2;
            const int zc = min(max(zraw, 0), 47);
            const bool zval = (zraw >= 0) && (zraw < 48);
#pragma unroll
            for (int yy = 0; yy < 2; yy++) {
              const int yrow = 2 * wp + yy + dy;     // 0..11
              const int rowoff = (yrow * 48 + zc) * 64;
#pragma unroll
              for (int kc = 0; kc < KC; kc++) {
                int u = (4 * kc + kg) ^ (zc & 7);
                bf16x8 v = *(const bf16x8*)(Albs_s + rowoff + u * 8);
                afr[yy][zt][kc] = zval ? v : (bf16x8)(short)0;
              }
            }
          }
          // ---- 24 MFMAs (NTH=2) ----
#pragma unroll
          for (int yy = 0; yy < 2; yy++)
#pragma unroll
            for (int zt = 0; zt < 3; zt++)
#pragma unroll
              for (int nt = 0; nt < NTH; nt++)
#pragma unroll
                for (int kc = 0; kc < KC; kc++)
                  acc[yy][zt][nt] = __builtin_amdgcn_mfma_f32_16x16x32_bf16(
                      afr[yy][zt][kc], bfr[nt * KC + kc], acc[yy][zt][nt], 0, 0, 0);
        }
      }
    }
  }
#undef LOADP

  if constexpr (MODE == 0) {
    __syncthreads();                            // all waves done reading Albs
    float* base = (float*)Albs;                 // 2 x (4 pairs x 1536 f) alias
    int par = 0;
#pragma unroll
    for (int yy = 0; yy < 2; yy++) {
#pragma unroll
      for (int zt = 0; zt < 3; zt++) {
        float* my = base + par * 6144 + wp * 1536;
        unsigned int* myO = (unsigned int*)(my + 1024);
        // both co-half waves write their quadrants (static acc idx, swizzled)
#pragma unroll
        for (int nt = 0; nt < NTH; nt++)
          *(f32x4*)(my + (co_off + lm + 16 * nt) * 16 + ((kg ^ (lm & 3)) << 2)) =
              acc[yy][zt][nt];
        __syncthreads();
        if (ch == 0 && l < 16) gate_tile(my, myO, l);
        __syncthreads();
        // paired copy: each wave moves 256 contiguous dwords (unswizzle read)
        unsigned int* gout = (unsigned int*)out_ +
            ((size_t)(((n * 48 + x) * 48 + (8 * yb + 2 * wp + yy)) * 48 + 16 * zt)) * 32;
#pragma unroll
        for (int q = 0; q < 4; q++) {
          int e = ch * 256 + q * 64 + l;
          gout[e] = myO[uidx(e)];
        }
        par ^= 1;
      }
    }
  } else {
    // layer 4: channel co=lm lives in lanes {lm, lm+16, lm+32, lm+48}
    if (w < 4) {
      float s = 0.f;
#pragma unroll
      for (int yy = 0; yy < 2; yy++)
#pragma unroll
        for (int zt = 0; zt < 3; zt++)
#pragma unroll
          for (int r = 0; r < 4; r++) s += acc[yy][zt][0][r];
      s += __shfl_xor(s, 16);
      s += __shfl_xor(s, 32);
      if (l < 7) atomicAdd(&((float*)out_)[n * 7 + l], s);
    }
  }
}

// Layer 0 (CIN=1): taps packed into MFMA-K (round-7 structure; writes the
// 64-ch padded activation layout via the shared epilogue).
__global__ __launch_bounds__(256, 4)
void conv0_mfma(const float* __restrict__ in_, const short* __restrict__ wb0L,
                unsigned short* __restrict__ out_) {
  __shared__ float A0[8 * 72];                 // [yi][zz] fp32, zz 52..71 = 0
  __shared__ __align__(16) float outbuf0[4 * 1536];

  const int tid = threadIdx.x;
  const int l = tid & 63;
  const int w = tid >> 6;
  const int lm = l & 15;
  const int kg = l >> 4;
  const int yb = blockIdx.x % 12;
  const int x = (blockIdx.x / 12) % 48;
  const int n = blockIdx.x / (12 * 48);

  f32x4 acc[3][4];
#pragma unroll
  for (int zt = 0; zt < 3; zt++)
#pragma unroll
    for (int nt = 0; nt < 4; nt++) acc[zt][nt] = (f32x4){0.f, 0.f, 0.f, 0.f};

  for (int dxi = 0; dxi < 5; dxi++) {
    int xin = x + dxi - 2;
    if (xin < 0 || xin >= 48) continue;
    __syncthreads();
    for (int e = tid; e < 8 * 72; e += 256) {
      int yi = e / 72, zz = e % 72;
      int yin = 4 * yb + yi - 2, zin = zz - 2;
      A0[e] = (yin >= 0 && yin < 48 && zin >= 0 && zin < 48)
                  ? in_[(size_t)((n * 48 + xin) * 48 + yin) * 48 + zin] : 0.f;
    }
    __syncthreads();
#pragma unroll
    for (int mf = 0; mf < 2; mf++) {
      const short* wbp = wb0L + ((size_t)(dxi * 2 + mf) * 64 + lm) * 32 + kg * 8;
      bf16x8 bfr[4];
#pragma unroll
      for (int nt = 0; nt < 4; nt++) bfr[nt] = *(const bf16x8*)(wbp + nt * 16 * 32);
      const int row = mf ? (w + 4) : (w + kg);
#pragma unroll
      for (int zt = 0; zt < 3; zt++) {
        const float* ap = A0 + row * 72 + 16 * zt + lm;
        union { bf16x8 v; unsigned short s[8]; } af;
#pragma unroll
        for (int j = 0; j < 8; j++) {
          __hip_bfloat16 h = __float2bfloat16(ap[j]);
          af.s[j] = *(unsigned short*)&h;
        }
#pragma unroll
        for (int nt = 0; nt < 4; nt++)
          acc[zt][nt] = __builtin_amdgcn_mfma_f32_16x16x32_bf16(
              af.v, bfr[nt], acc[zt][nt], 0, 0, 0);
      }
    }
  }

  float* my = outbuf0 + w * 1536;
  epilogue_gate<4>(acc, my, out_, n, x, 4 * yb + w, l, lm, kg);
}

extern "C" void kernel_launch(void* const* d_in, const int* in_sizes, int n_in,
                              void* d_out, int out_size, void* d_ws, size_t ws_size,
                              hipStream_t stream) {
  // setup_inputs() dict order (INTERLEAVED): x, tp_w0, lin_w0, tp_w1, lin_w1, ...
  const float* x   = (const float*)d_in[0];
  const float* tw0 = (const float*)d_in[1];
  const float* lw0 = (const float*)d_in[2];
  const float* tw1 = (const float*)d_in[3];
  const float* lw1 = (const float*)d_in[4];
  const float* tw2 = (const float*)d_in[5];
  const float* lw2 = (const float*)d_in[6];
  const float* tw3 = (const float*)d_in[7];
  const float* lw3 = (const float*)d_in[8];
  const float* tw4 = (const float*)d_in[9];
  const float* lw4 = (const float*)d_in[10];

  float* ws = (float*)d_ws;
  float* k0 = ws;                 // 125*1*60   = 7500
  float* k1 = k0 + 7500;          // 125*50*60  = 375000
  float* k2 = k1 + 375000;
  float* k3 = k2 + 375000;
  float* k4 = k3 + 375000;        // 125*50*7   = 43750  (end: 1,176,250)
  // 64-ch-padded bf16 activations: 2*48^3*64 = 14,155,776 ushorts each
  unsigned short* actA = (unsigned short*)(ws + 1200000);
  unsigned short* actB = actA + 14155776;     // ends float offset 15,355,776
  // bf16 transposed weights [125][64][64] per layer
  unsigned short* wb1 = (unsigned short*)(ws + 15360000);
  unsigned short* wb2 = wb1 + 512000;
  unsigned short* wb3 = wb2 + 512000;
  unsigned short* wb4 = wb3 + 512000;
  unsigned short* wb0L = wb4 + 512000;        // [5][2][64][32] = 20480

  hipMemsetAsync(ws, 0, (size_t)1176250 * sizeof(float), stream);
  hipMemsetAsync(d_out, 0, (size_t)out_size * sizeof(float), stream);

  build_tp_kernel<<<3, 128, 0, stream>>>(tw0, k0, 1, 60, 0);
  build_tp_kernel<<<12, 128, 0, stream>>>(tw1, k1, 50, 60, 3);
  build_tp_kernel<<<12, 128, 0, stream>>>(tw2, k2, 50, 60, 3);
  build_tp_kernel<<<12, 128, 0, stream>>>(tw3, k3, 50, 60, 3);
  build_tp_kernel<<<4, 128, 0, stream>>>(tw4, k4, 50, 7, 15);
  set_center_kernel<<<1, 256, 0, stream>>>(lw0, k0, 1, 60, 0, 2);
  set_center_kernel<<<1, 256, 0, stream>>>(lw1, k1, 50, 60, 2, 5);
  set_center_kernel<<<1, 256, 0, stream>>>(lw2, k2, 50, 60, 2, 5);
  set_center_kernel<<<1, 256, 0, stream>>>(lw3, k3, 50, 60, 2, 5);
  set_center_kernel<<<1, 256, 0, stream>>>(lw4, k4, 50, 7, 7, 2);

  convert_w<<<2000, 256, 0, stream>>>(k1, wb1, 50, 60);
  convert_w<<<2000, 256, 0, stream>>>(k2, wb2, 50, 60);
  convert_w<<<2000, 256, 0, stream>>>(k3, wb3, 50, 60);
  convert_w<<<2000, 256, 0, stream>>>(k4, wb4, 50, 7);
  build_w0<<<80, 256, 0, stream>>>(k0, wb0L);

  const int grid0 = 2 * 48 * 12;  // conv0: (n, x, y-quad), 1 y per wave
  const int grid  = 2 * 48 * 6;   // mid/last: (n, x, y-octant), 512 thr
  conv0_mfma<<<grid0, 256, 0, stream>>>(x, (const short*)wb0L, actA);
  conv_mfma<50, 60, 0><<<grid, 512, 0, stream>>>(actA, (const short*)wb1, actB);
  conv_mfma<50, 60, 0><<<grid, 512, 0, stream>>>(actB, (const short*)wb2, actA);
  conv_mfma<50, 60, 0><<<grid, 512, 0, stream>>>(actA, (const short*)wb3, actB);
  conv_mfma<50, 7, 1><<<grid, 512, 0, stream>>>(actB, (const short*)wb4, d_out);
}